// Round 11
// baseline (27.134 us; speedup 1.0000x reference)
//
#include <hip/hip_runtime.h>
#include <math.h>

#define DIM 16

// ---------------------------------------------------------------------------
// Fully fused kernel. Each block:
//   Phase A (redundant per block, ~sub-µs): build C[4][81] in LDS.
//     - 16 threads evolve the 16 unitary columns of the 2-layer
//       StronglyEntanglingLayers circuit entirely in registers (unrolled
//       butterflies, CNOT swaps = register renames), write U to LDS.
//     - 256 threads: Ad[i][j][k] = Re(U^dag Z_i U) via shared 16-products.
//     - sparse contraction Ad -> C (16-term signed sums, bit arithmetic).
//   Phase B: 4 patches per thread; out_i = sum_v C_i[v] prod_q g_{v_q}(t_q),
//     g=(1,cos t,sin t), t=tanh(p)*pi/2. Each C value is ONE uniform
//     (broadcast) ds_read reused in 4 FMAs -> FMA-issue-bound, not LDS-bound.
// One dispatch: no inter-kernel bubble, no second launch, no C global trip.
// ---------------------------------------------------------------------------
static __device__ __forceinline__ void pix_trig(float xx, float& c, float& s) {
  xx = fminf(10.0f, fmaxf(-10.0f, xx));            // v_med3
  const float u = __expf(xx + xx);                 // v_exp
  const float th = (u - 1.0f) * __builtin_amdgcn_rcpf(u + 1.0f);
  __sincosf(th * 1.57079632679489662f, &s, &c);    // hw v_sin/v_cos
}

__global__ __launch_bounds__(256) void quanv_fused(const float* __restrict__ x,
                                                   const float* __restrict__ w,
                                                   float* __restrict__ out) {
  __shared__ float Ur[DIM][20];
  __shared__ float Ui[DIM][20];
  __shared__ float Ad[4][DIM][DIM];
  __shared__ float Cs[4 * 81];
  const int tid = threadIdx.x;

  // ---- Phase A1: column evolution in registers (16 threads) ----
  if (tid < DIM) {
    float ur[DIM], ui[DIM];
#pragma unroll
    for (int m = 0; m < DIM; ++m) { ur[m] = (m == tid) ? 1.0f : 0.0f; ui[m] = 0.0f; }
#pragma unroll
    for (int l = 0; l < 2; ++l) {
#pragma unroll
      for (int q = 0; q < 4; ++q) {
        const float phi = w[l * 12 + q * 3 + 0];
        const float th  = w[l * 12 + q * 3 + 1];
        const float om  = w[l * 12 + q * 3 + 2];
        const float a  = 0.5f * (phi + om);
        const float bb = 0.5f * (phi - om);
        float ct, st, ca, sa, cb, sb;
        __sincosf(0.5f * th, &st, &ct);
        __sincosf(a, &sa, &ca);
        __sincosf(bb, &sb, &cb);
        const float g00r =  ca * ct, g00i = -sa * ct;   // e^{-ia} ct
        const float g01r = -cb * st, g01i = -sb * st;   // -e^{+ib} st
        const float g10r =  cb * st, g10i = -sb * st;   // e^{-ib} st
        const float g11r =  ca * ct, g11i =  sa * ct;   // e^{+ia} ct
        const int bit = 1 << (3 - q);
#pragma unroll
        for (int m = 0; m < DIM; ++m) {
          if (m & bit) continue;
          const int m1 = m | bit;
          const float v0r = ur[m],  v0i = ui[m];
          const float v1r = ur[m1], v1i = ui[m1];
          ur[m]  = g00r * v0r - g00i * v0i + g01r * v1r - g01i * v1i;
          ui[m]  = g00r * v0i + g00i * v0r + g01r * v1i + g01i * v1r;
          ur[m1] = g10r * v0r - g10i * v0i + g11r * v1r - g11i * v1i;
          ui[m1] = g10r * v0i + g10i * v0r + g11r * v1i + g11i * v1r;
        }
      }
      const int r = (l % 3) + 1;
#pragma unroll
      for (int q = 0; q < 4; ++q) {
        const int cbit = 1 << (3 - q);
        const int tbit = 1 << (3 - ((q + r) & 3));
#pragma unroll
        for (int m = 0; m < DIM; ++m) {
          if ((m & cbit) && !(m & tbit)) {
            const int m1 = m | tbit;
            float t;
            t = ur[m]; ur[m] = ur[m1]; ur[m1] = t;
            t = ui[m]; ui[m] = ui[m1]; ui[m1] = t;
          }
        }
      }
    }
#pragma unroll
    for (int m = 0; m < DIM; ++m) { Ur[tid][m] = ur[m]; Ui[tid][m] = ui[m]; }
  }
  __syncthreads();

  // ---- Phase A2: Ad[i][j][k] ----
  {
    const int j = tid >> 4, k = tid & 15;
    float term[DIM];
#pragma unroll
    for (int m = 0; m < DIM; ++m)
      term[m] = Ur[j][m] * Ur[k][m] + Ui[j][m] * Ui[k][m];
#pragma unroll
    for (int i = 0; i < 4; ++i) {
      float s = 0.0f;
#pragma unroll
      for (int m = 0; m < DIM; ++m)
        s += ((m >> (3 - i)) & 1) ? -term[m] : term[m];
      Ad[i][j][k] = s;
    }
  }
  __syncthreads();

  // ---- Phase A3: contract Ad -> Cs[4][81] ----
  for (int idx = tid; idx < 4 * 81; idx += 256) {
    const int i = idx / 81;
    const int rr = idx - i * 81;
    const int v0 = rr / 27, v1 = (rr / 9) % 3, v2 = (rr / 3) % 3, v3 = rr % 3;
    float s = 0.0f;
#pragma unroll
    for (int b = 0; b < 16; ++b) {
      const int b0 = (b >> 3) & 1, b1 = (b >> 2) & 1, b2 = (b >> 1) & 1, b3 = b & 1;
      const int k0 = (v0 == 2) ? (b0 ^ 1) : b0;
      const int k1 = (v1 == 2) ? (b1 ^ 1) : b1;
      const int k2 = (v2 == 2) ? (b2 ^ 1) : b2;
      const int k3 = (v3 == 2) ? (b3 ^ 1) : b3;
      const int neg = (((v0 == 1) & b0) ^ ((v1 == 1) & b1) ^
                       ((v2 == 1) & b2) ^ ((v3 == 1) & b3));
      const int k = (k0 << 3) | (k1 << 2) | (k2 << 1) | k3;
      const float term = Ad[i][b][k];
      s += neg ? -term : term;
    }
    Cs[idx] = 0.0625f * s;
  }
  __syncthreads();

  // ---- Phase B: 4 patches per thread ----
  const int base_pid = blockIdx.x * 1024 + tid;    // 784 blocks * 1024 = 802816
  float g0[4][3], g1[4][3], g2[4][3], c3a[4], s3a[4];
  int obase[4];
#pragma unroll
  for (int p = 0; p < 4; ++p) {
    const int pid = base_pid + p * 256;
    const int b   = pid / 12544;                   // 112*112
    const int rem = pid - b * 12544;
    const int i   = rem / 112;
    const int j   = rem - i * 112;
    const float* px = x + (size_t)b * 50176 + (size_t)(2 * i) * 224 + 2 * j;
    const float2 r0 = *(const float2*)(px);
    const float2 r1 = *(const float2*)(px + 224);
    float c0, s0, c1, s1, c2, s2, c3, s3;
    pix_trig(r0.x, c0, s0);
    pix_trig(r0.y, c1, s1);
    pix_trig(r1.x, c2, s2);
    pix_trig(r1.y, c3, s3);
    g0[p][0] = 1.0f; g0[p][1] = c0; g0[p][2] = s0;
    g1[p][0] = 1.0f; g1[p][1] = c1; g1[p][2] = s1;
    g2[p][0] = 1.0f; g2[p][1] = c2; g2[p][2] = s2;
    c3a[p] = c3; s3a[p] = s3;
    obase[p] = b * 50176 + i * 112 + j;            // out b-stride = 4*12544 = 50176
  }

#pragma unroll
  for (int oi = 0; oi < 4; ++oi) {
    float a0[4], a1[4], a2[4];
#pragma unroll
    for (int v0 = 0; v0 < 3; ++v0) {
#pragma unroll
      for (int v1 = 0; v1 < 3; ++v1) {
#pragma unroll
        for (int v2 = 0; v2 < 3; ++v2) {
          const int base = oi * 81 + ((v0 * 3 + v1) * 3 + v2) * 3;
          const float d0 = Cs[base], d1 = Cs[base + 1], d2 = Cs[base + 2];
#pragma unroll
          for (int p = 0; p < 4; ++p) {
            const float t = fmaf(s3a[p], d2, fmaf(c3a[p], d1, d0));
            a2[p] = (v2 == 0) ? t : fmaf(g2[p][v2], t, a2[p]);
          }
        }
#pragma unroll
        for (int p = 0; p < 4; ++p)
          a1[p] = (v1 == 0) ? a2[p] : fmaf(g1[p][v1], a2[p], a1[p]);
      }
#pragma unroll
      for (int p = 0; p < 4; ++p)
        a0[p] = (v0 == 0) ? a1[p] : fmaf(g0[p][v0], a1[p], a0[p]);
    }
#pragma unroll
    for (int p = 0; p < 4; ++p)
      out[obase[p] + oi * 12544] = a0[p];
  }
}

extern "C" void kernel_launch(void* const* d_in, const int* in_sizes, int n_in,
                              void* d_out, int out_size, void* d_ws, size_t ws_size,
                              hipStream_t stream) {
  const float* x = (const float*)d_in[0];   // (64,1,224,224) f32
  const float* w = (const float*)d_in[1];   // (2,4,3) f32
  float* out = (float*)d_out;               // (64,4,112,112) f32

  quanv_fused<<<784, 256, 0, stream>>>(x, w, out);
}

// Round 12
// 20.872 us; speedup vs baseline: 1.3000x; 1.3000x over previous
//
#include <hip/hip_runtime.h>
#include <math.h>

#define DIM 16

typedef float v2f __attribute__((ext_vector_type(2)));
static __device__ __forceinline__ v2f vsplat(float v) { return (v2f){v, v}; }
static __device__ __forceinline__ v2f vfma(v2f a, v2f b, v2f c) {
  return __builtin_elementwise_fma(a, b, c);     // -> v_pk_fma_f32
}

// ---------------------------------------------------------------------------
// Precompute kernel (unchanged from R10 best): build C[4][81] into d_ws.
// Phase 1: 16 threads evolve unitary columns entirely in registers.
// Phase 2: thread (j,k) -> Ad[i][j][k]. Phase 3: sparse contraction -> C.
// ---------------------------------------------------------------------------
__global__ __launch_bounds__(256) void quanv_precompute(const float* __restrict__ w,
                                                        float* __restrict__ C) {
  __shared__ float Ur[DIM][20];
  __shared__ float Ui[DIM][20];
  __shared__ float Ad[4][DIM][DIM];
  const int tid = threadIdx.x;

  if (tid < DIM) {
    float ur[DIM], ui[DIM];
#pragma unroll
    for (int m = 0; m < DIM; ++m) { ur[m] = (m == tid) ? 1.0f : 0.0f; ui[m] = 0.0f; }
#pragma unroll
    for (int l = 0; l < 2; ++l) {
#pragma unroll
      for (int q = 0; q < 4; ++q) {
        const float phi = w[l * 12 + q * 3 + 0];
        const float th  = w[l * 12 + q * 3 + 1];
        const float om  = w[l * 12 + q * 3 + 2];
        const float a  = 0.5f * (phi + om);
        const float bb = 0.5f * (phi - om);
        float ct, st, ca, sa, cb, sb;
        __sincosf(0.5f * th, &st, &ct);
        __sincosf(a, &sa, &ca);
        __sincosf(bb, &sb, &cb);
        const float g00r =  ca * ct, g00i = -sa * ct;
        const float g01r = -cb * st, g01i = -sb * st;
        const float g10r =  cb * st, g10i = -sb * st;
        const float g11r =  ca * ct, g11i =  sa * ct;
        const int bit = 1 << (3 - q);
#pragma unroll
        for (int m = 0; m < DIM; ++m) {
          if (m & bit) continue;
          const int m1 = m | bit;
          const float v0r = ur[m],  v0i = ui[m];
          const float v1r = ur[m1], v1i = ui[m1];
          ur[m]  = g00r * v0r - g00i * v0i + g01r * v1r - g01i * v1i;
          ui[m]  = g00r * v0i + g00i * v0r + g01r * v1i + g01i * v1r;
          ur[m1] = g10r * v0r - g10i * v0i + g11r * v1r - g11i * v1i;
          ui[m1] = g10r * v0i + g10i * v0r + g11r * v1i + g11i * v1r;
        }
      }
      const int r = (l % 3) + 1;
#pragma unroll
      for (int q = 0; q < 4; ++q) {
        const int cbit = 1 << (3 - q);
        const int tbit = 1 << (3 - ((q + r) & 3));
#pragma unroll
        for (int m = 0; m < DIM; ++m) {
          if ((m & cbit) && !(m & tbit)) {
            const int m1 = m | tbit;
            float t;
            t = ur[m]; ur[m] = ur[m1]; ur[m1] = t;
            t = ui[m]; ui[m] = ui[m1]; ui[m1] = t;
          }
        }
      }
    }
#pragma unroll
    for (int m = 0; m < DIM; ++m) { Ur[tid][m] = ur[m]; Ui[tid][m] = ui[m]; }
  }
  __syncthreads();

  {
    const int j = tid >> 4, k = tid & 15;
    float term[DIM];
#pragma unroll
    for (int m = 0; m < DIM; ++m)
      term[m] = Ur[j][m] * Ur[k][m] + Ui[j][m] * Ui[k][m];
#pragma unroll
    for (int i = 0; i < 4; ++i) {
      float s = 0.0f;
#pragma unroll
      for (int m = 0; m < DIM; ++m)
        s += ((m >> (3 - i)) & 1) ? -term[m] : term[m];
      Ad[i][j][k] = s;
    }
  }
  __syncthreads();

  for (int idx = tid; idx < 4 * 81; idx += 256) {
    const int i = idx / 81;
    const int rr = idx - i * 81;
    const int v0 = rr / 27, v1 = (rr / 9) % 3, v2 = (rr / 3) % 3, v3 = rr % 3;
    float s = 0.0f;
#pragma unroll
    for (int b = 0; b < 16; ++b) {
      const int b0 = (b >> 3) & 1, b1 = (b >> 2) & 1, b2 = (b >> 1) & 1, b3 = b & 1;
      const int k0 = (v0 == 2) ? (b0 ^ 1) : b0;
      const int k1 = (v1 == 2) ? (b1 ^ 1) : b1;
      const int k2 = (v2 == 2) ? (b2 ^ 1) : b2;
      const int k3 = (v3 == 2) ? (b3 ^ 1) : b3;
      const int neg = (((v0 == 1) & b0) ^ ((v1 == 1) & b1) ^
                       ((v2 == 1) & b2) ^ ((v3 == 1) & b3));
      const int k = (k0 << 3) | (k1 << 2) | (k2 << 1) | k3;
      const float term = Ad[i][b][k];
      s += neg ? -term : term;
    }
    C[idx] = 0.0625f * s;
  }
}

// ---------------------------------------------------------------------------
// Main kernel: TWO horizontally-adjacent patches per thread, evaluated as
// float2 SIMD in-lane -> v_pk_fma_f32 halves VALU issue per patch.
// C reads stay wave-uniform scalar loads (SGPR operands of the pk-FMAs).
// Input: one float4 per patch row (16B/lane). Output: float2 per plane.
// ---------------------------------------------------------------------------
static __device__ __forceinline__ void pix_trig(float xx, float& c, float& s) {
  xx = fminf(10.0f, fmaxf(-10.0f, xx));            // v_med3
  const float u = __expf(xx + xx);                 // v_exp
  const float th = (u - 1.0f) * __builtin_amdgcn_rcpf(u + 1.0f);
  __sincosf(th * 1.57079632679489662f, &s, &c);    // hw v_sin/v_cos
}

__global__ __launch_bounds__(256) void quanv_main(const float* __restrict__ x,
                                                  const float* __restrict__ C,
                                                  float* __restrict__ out) {
  const int P  = blockIdx.x * 256 + threadIdx.x;   // 401408 pair-ids (1568 blocks)
  const int b  = P / 6272;                         // 112*56 pairs per image
  const int rm = P - b * 6272;
  const int i  = rm / 56;
  const int jp = rm - i * 56;                      // pair col; patches j=2jp, 2jp+1

  const float* px = x + (size_t)b * 50176 + (size_t)(2 * i) * 224 + 4 * jp;
  const float4 r0 = *(const float4*)(px);          // patch0: .x.y  patch1: .z.w
  const float4 r1 = *(const float4*)(px + 224);

  float c0a, s0a, c1a, s1a, c2a, s2a, c3a, s3a;    // patch0 (left)
  float c0b, s0b, c1b, s1b, c2b, s2b, c3b, s3b;    // patch1 (right)
  pix_trig(r0.x, c0a, s0a);
  pix_trig(r0.y, c1a, s1a);
  pix_trig(r1.x, c2a, s2a);
  pix_trig(r1.y, c3a, s3a);
  pix_trig(r0.z, c0b, s0b);
  pix_trig(r0.w, c1b, s1b);
  pix_trig(r1.z, c2b, s2b);
  pix_trig(r1.w, c3b, s3b);

  const v2f g0v[3] = {vsplat(1.0f), (v2f){c0a, c0b}, (v2f){s0a, s0b}};
  const v2f g1v[3] = {vsplat(1.0f), (v2f){c1a, c1b}, (v2f){s1a, s1b}};
  const v2f g2v[3] = {vsplat(1.0f), (v2f){c2a, c2b}, (v2f){s2a, s2b}};
  const v2f c3v = (v2f){c3a, c3b};
  const v2f s3v = (v2f){s3a, s3b};

  const int obase = b * 50176 + i * 112 + 2 * jp;  // out b-stride 4*12544

#pragma unroll
  for (int oi = 0; oi < 4; ++oi) {
    const float* D = C + oi * 81;
    v2f a0, a1, a2;
#pragma unroll
    for (int v0 = 0; v0 < 3; ++v0) {
#pragma unroll
      for (int v1 = 0; v1 < 3; ++v1) {
#pragma unroll
        for (int v2 = 0; v2 < 3; ++v2) {
          const int base = ((v0 * 3 + v1) * 3 + v2) * 3;
          const float d0 = D[base], d1 = D[base + 1], d2 = D[base + 2];
          const v2f t = vfma(s3v, vsplat(d2), vfma(c3v, vsplat(d1), vsplat(d0)));
          a2 = (v2 == 0) ? t : vfma(g2v[v2], t, a2);
        }
        a1 = (v1 == 0) ? a2 : vfma(g1v[v1], a2, a1);
      }
      a0 = (v0 == 0) ? a1 : vfma(g0v[v0], a1, a0);
    }
    *(float2*)(&out[obase + oi * 12544]) = (float2){a0.x, a0.y};
  }
}

extern "C" void kernel_launch(void* const* d_in, const int* in_sizes, int n_in,
                              void* d_out, int out_size, void* d_ws, size_t ws_size,
                              hipStream_t stream) {
  const float* x = (const float*)d_in[0];   // (64,1,224,224) f32
  const float* w = (const float*)d_in[1];   // (2,4,3) f32
  float* out = (float*)d_out;               // (64,4,112,112) f32
  float* C   = (float*)d_ws;                // 4*81 floats

  quanv_precompute<<<1, 256, 0, stream>>>(w, C);
  quanv_main<<<1568, 256, 0, stream>>>(x, C, out);
}